// Round 10
// baseline (49.132 us; speedup 1.0000x reference)
//
#include <hip/hip_runtime.h>
#include <hip/hip_bf16.h>

// SimCLR NT-Xent loss v10: m201-style 256x256 8-wave phase-pipelined GEMM
// (BK=64, dbuf 128KB LDS, A and B both LDS-staged with T2 XOR swizzle via
// pre-swizzled gload_lds sources), LSE entirely in epilogue (no in-loop VALU),
// per-(row, q, wc) partials -> rowloss merge.

#define NROWS 4096
#define DDIM  512
#define NSLOT 64                 // 16 colsplits x 4 col-waves
#define NEG_BIG (-3.0e38f)
#define SQRT_CSCALE 3.798282562f // sqrt(10*log2(e)); (cA)(cB) = 10*log2(e)*sim
#define LN2 0.69314718055994530942f

typedef __bf16 bf16x8 __attribute__((ext_vector_type(8)));
typedef float  f32x4  __attribute__((ext_vector_type(4)));

#define GLOAD_LDS16(g, l) __builtin_amdgcn_global_load_lds(                    \
    (const __attribute__((address_space(1))) void*)(g),                        \
    (__attribute__((address_space(3))) void*)(l), 16, 0, 0)

#define MFMA16(a, b, c) __builtin_amdgcn_mfma_f32_16x16x32_bf16((a), (b), (c), 0, 0, 0)

// ---------------- kernel 0: fp32 -> bf16, scaled by sqrt(c) ----------------
__global__ void jl_cvt(const float* __restrict__ in, __bf16* __restrict__ out) {
    int i = (blockIdx.x * 256 + threadIdx.x) * 8;
    float4 a = *(const float4*)(in + i);
    float4 b = *(const float4*)(in + i + 4);
    bf16x8 w;
    w[0] = (__bf16)(a.x * SQRT_CSCALE); w[1] = (__bf16)(a.y * SQRT_CSCALE);
    w[2] = (__bf16)(a.z * SQRT_CSCALE); w[3] = (__bf16)(a.w * SQRT_CSCALE);
    w[4] = (__bf16)(b.x * SQRT_CSCALE); w[5] = (__bf16)(b.y * SQRT_CSCALE);
    w[6] = (__bf16)(b.z * SQRT_CSCALE); w[7] = (__bf16)(b.w * SQRT_CSCALE);
    *(bf16x8*)(out + i) = w;
}

// ---------------- kernel 1: 256x256 phase-pipelined GEMM + epilogue LSE ----------------
// grid = 16x16 = 256 blocks (1/CU), 512 threads (8 waves, 2 row x 4 col).
// block (rbk,q): rows [rbk*256,+256) x cols [q*256,+256); K = 512, 8 K-tiles of 64.
__global__ __launch_bounds__(512, 2) void jl_main(const __bf16* __restrict__ rb,
                                                  float* __restrict__ pm,
                                                  float* __restrict__ ps,
                                                  float* __restrict__ pos) {
    // [buf][A=0/B=1][256 rows][128 B], XOR-swizzled 16B slots within each row
    __shared__ __align__(16) char lds[2][2][256 * 128];

    const int rbk  = blockIdx.x >> 4;
    const int q    = blockIdx.x & 15;
    const int wave = threadIdx.x >> 6;
    const int lane = threadIdx.x & 63;
    const int wr   = wave >> 2;          // 0..1  (row half)
    const int wc   = wave & 3;           // 0..3  (col quarter)
    const int lrow = lane & 15;
    const int lk   = lane >> 4;

    const int row0 = rbk * 256;
    const int col0 = q * 256;
    const char* rbb = (const char*)rb;   // row stride 1024 B

    // stage source: wave stages rows [wave*32, +32) of A-tile and B-tile,
    // 4 gload_lds each (8 rows / 1KB per instr). Pre-swizzled global source:
    const int srow = wave * 32 + (lane >> 3);                    // + 8*i
    const int ssw  = ((lane & 7) << 4) ^ (((lane >> 3) & 7) << 4);
    const char* gA = rbb + (size_t)(row0 + srow) * 1024 + ssw;
    const char* gB = rbb + (size_t)(col0 + srow) * 1024 + ssw;

    // stage pair i (A row-group i and B row-group i) of K-tile T
#define STAGEP(T, i)                                                           \
    do {                                                                       \
        GLOAD_LDS16(gA + (size_t)(T) * 128 + (i) * 8192,                       \
                    &lds[(T) & 1][0][(wave * 32 + 8 * (i)) * 128]);            \
        GLOAD_LDS16(gB + (size_t)(T) * 128 + (i) * 8192,                       \
                    &lds[(T) & 1][1][(wave * 32 + 8 * (i)) * 128]);            \
    } while (0)

    // swizzled LDS read offsets
    const int rswz = (lrow & 7) << 4;
#define AOFF(fr, kb) (((wr * 128 + (fr) * 16 + lrow) * 128) + ((((kb) * 64) + lk * 16) ^ rswz))
#define BOFF(fc, kb) (((wc * 64 + (fc) * 16 + lrow) * 128) + ((((kb) * 64) + lk * 16) ^ rswz))

    f32x4 acc[8][4];
    #pragma unroll
    for (int fr = 0; fr < 8; ++fr)
        #pragma unroll
        for (int fc = 0; fc < 4; ++fc)
            acc[fr][fc] = (f32x4){0.f, 0.f, 0.f, 0.f};

    // prologue: stage K-tile 0
    #pragma unroll
    for (int i = 0; i < 4; ++i) STAGEP(0, i);

    for (int t = 0; t < 8; ++t) {
        asm volatile("s_waitcnt vmcnt(0)" ::: "memory");
        __builtin_amdgcn_s_barrier();
        __builtin_amdgcn_sched_barrier(0);

        const char* ldsA = &lds[t & 1][0][0];
        const char* ldsB = &lds[t & 1][1][0];
        bf16x8 bfr[4][2];

        #pragma unroll
        for (int p = 0; p < 4; ++p) {
            if (p == 0) {
                #pragma unroll
                for (int fc = 0; fc < 4; ++fc) {
                    bfr[fc][0] = *(const bf16x8*)(ldsB + BOFF(fc, 0));
                    bfr[fc][1] = *(const bf16x8*)(ldsB + BOFF(fc, 1));
                }
            }
            bf16x8 a00 = *(const bf16x8*)(ldsA + AOFF(2 * p,     0));
            bf16x8 a01 = *(const bf16x8*)(ldsA + AOFF(2 * p,     1));
            bf16x8 a10 = *(const bf16x8*)(ldsA + AOFF(2 * p + 1, 0));
            bf16x8 a11 = *(const bf16x8*)(ldsA + AOFF(2 * p + 1, 1));

            // front-load next-tile staging into phases 0-1 (latency cover)
            if (p < 2 && t < 7) {
                STAGEP(t + 1, 2 * p);
                STAGEP(t + 1, 2 * p + 1);
            }

            __builtin_amdgcn_s_barrier();
            asm volatile("s_waitcnt lgkmcnt(0)" ::: "memory");
            __builtin_amdgcn_sched_barrier(0);

            __builtin_amdgcn_s_setprio(1);
            #pragma unroll
            for (int fc = 0; fc < 4; ++fc) {
                acc[2 * p][fc]     = MFMA16(a00, bfr[fc][0], acc[2 * p][fc]);
                acc[2 * p][fc]     = MFMA16(a01, bfr[fc][1], acc[2 * p][fc]);
                acc[2 * p + 1][fc] = MFMA16(a10, bfr[fc][0], acc[2 * p + 1][fc]);
                acc[2 * p + 1][fc] = MFMA16(a11, bfr[fc][1], acc[2 * p + 1][fc]);
            }
            __builtin_amdgcn_s_setprio(0);
            __builtin_amdgcn_s_barrier();
        }
    }
#undef STAGEP

    // ---------------- epilogue: diagonal mask, pos extract, per-row (m,s) ----------------
    const bool isdiag = (rbk == q);
    const bool ispos  = (q == (rbk ^ 8));   // partner bit: 2048 = 8*256

    #pragma unroll
    for (int fr = 0; fr < 8; ++fr) {
        #pragma unroll
        for (int r = 0; r < 4; ++r) {
            const int rr = wr * 128 + fr * 16 + 4 * lk + r;   // in-block row
            float v0 = acc[fr][0][r], v1 = acc[fr][1][r];
            float v2 = acc[fr][2][r], v3 = acc[fr][3][r];
            if (ispos | isdiag) {
                const int cb = wc * 64 + lrow;                 // + fc*16
                #pragma unroll
                for (int fc = 0; fc < 4; ++fc) {
                    float* vp = (fc == 0) ? &v0 : (fc == 1) ? &v1 : (fc == 2) ? &v2 : &v3;
                    if (cb + fc * 16 == rr) {
                        if (ispos) pos[row0 + rr] = *vp;
                        if (isdiag) *vp = NEG_BIG;
                    }
                }
            }
            float mm = fmaxf(fmaxf(v0, v1), fmaxf(v2, v3));
            float ss = __builtin_amdgcn_exp2f(v0 - mm) + __builtin_amdgcn_exp2f(v1 - mm)
                     + __builtin_amdgcn_exp2f(v2 - mm) + __builtin_amdgcn_exp2f(v3 - mm);
            #pragma unroll
            for (int off = 1; off < 16; off <<= 1) {
                float mo = __shfl_xor(mm, off, 64);
                float so = __shfl_xor(ss, off, 64);
                float mn = fmaxf(mm, mo);
                ss = ss * __builtin_amdgcn_exp2f(mm - mn) + so * __builtin_amdgcn_exp2f(mo - mn);
                mm = mn;
            }
            if (lrow == 0) {
                const int grow = row0 + rr;
                pm[grow * NSLOT + q * 4 + wc] = mm;
                ps[grow * NSLOT + q * 4 + wc] = ss;
            }
        }
    }
}

// ---------------- kernel 2a: per-row loss + per-block partial sum ----------------
__global__ void jl_rowloss(const float* __restrict__ pm, const float* __restrict__ ps,
                           const float* __restrict__ pos, float* __restrict__ part) {
    __shared__ float red[256];
    const int t = threadIdx.x;
    const int row = blockIdx.x * 256 + t;
    float mb = NEG_BIG;
    for (int qq = 0; qq < NSLOT; ++qq) mb = fmaxf(mb, pm[row * NSLOT + qq]);
    float st = 0.0f;
    for (int qq = 0; qq < NSLOT; ++qq)
        st += ps[row * NSLOT + qq] * __builtin_amdgcn_exp2f(pm[row * NSLOT + qq] - mb);
    red[t] = mb + __builtin_amdgcn_logf(st) - pos[row];
    __syncthreads();
    for (int off = 128; off > 0; off >>= 1) {
        if (t < off) red[t] += red[t + off];
        __syncthreads();
    }
    if (t == 0) part[blockIdx.x] = red[0];
}

// ---------------- kernel 2b: final reduce ----------------
__global__ void jl_final(const float* __restrict__ part, float* __restrict__ out) {
    const int t = threadIdx.x;
    float v = (t < NROWS / 256) ? part[t] : 0.0f;
    #pragma unroll
    for (int off = 1; off < 16; off <<= 1) v += __shfl_xor(v, off, 64);
    if (t == 0) out[0] = v * (LN2 / (float)NROWS);
}

extern "C" void kernel_launch(void* const* d_in, const int* in_sizes, int n_in,
                              void* d_out, int out_size, void* d_ws, size_t ws_size,
                              hipStream_t stream) {
    const float* rep = (const float*)d_in[0];
    float* out = (float*)d_out;

    __bf16* rbuf = (__bf16*)d_ws;                               // 4 MB
    float*  pm   = (float*)(rbuf + (size_t)NROWS * DDIM);       // 1 MB
    float*  ps   = pm + (size_t)NROWS * NSLOT;                  // 1 MB
    float*  pos  = ps + (size_t)NROWS * NSLOT;                  // 16 KB
    float*  part = pos + NROWS;

    jl_cvt<<<(NROWS * DDIM) / (256 * 8), 256, 0, stream>>>(rep, rbuf);
    jl_main<<<16 * 16, 512, 0, stream>>>(rbuf, pm, ps, pos);
    jl_rowloss<<<NROWS / 256, 256, 0, stream>>>(pm, ps, pos, part);
    jl_final<<<1, 64, 0, stream>>>(part, out);
}

// Round 11
// 44.937 us; speedup vs baseline: 1.0934x; 1.0934x over previous
//
#include <hip/hip_runtime.h>
#include <hip/hip_bf16.h>

// SimCLR NT-Xent loss v11: R9 base + true T4 — 4-slot LDS ring of 16-col
// K512 tiles (16KB each), prefetch depth 3, counted vmcnt(8/4/0) (never 0 in
// steady state), 1 barrier/tile. Coalesced swizzled staging, A resident.

#define NROWS 4096
#define DDIM  512
#define NSPLIT 16                // column splits (256 cols each)
#define NT 16                    // 16 tiles of 16 cols per block
#define BM 128                   // rows per block (4 waves x 32)
#define NEG_BIG (-3.0e38f)
#define SQRT_CSCALE 3.798282562f // sqrt(10*log2(e)); (cA)(cB) = 10*log2(e)*sim
#define LN2 0.69314718055994530942f
#define THR 40.0f                // defer-max threshold (log2 units)

typedef __bf16 bf16x8 __attribute__((ext_vector_type(8)));
typedef float  f32x4  __attribute__((ext_vector_type(4)));

#define GLOAD_LDS16(g, l) __builtin_amdgcn_global_load_lds(                    \
    (const __attribute__((address_space(1))) void*)(g),                        \
    (__attribute__((address_space(3))) void*)(l), 16, 0, 0)

#define MFMA16(a, b, c) __builtin_amdgcn_mfma_f32_16x16x32_bf16((a), (b), (c), 0, 0, 0)

// ---------------- kernel 0: fp32 -> bf16, scaled by sqrt(c) ----------------
__global__ void jl_cvt(const float* __restrict__ in, __bf16* __restrict__ out) {
    int i = (blockIdx.x * 256 + threadIdx.x) * 8;
    float4 a = *(const float4*)(in + i);
    float4 b = *(const float4*)(in + i + 4);
    bf16x8 w;
    w[0] = (__bf16)(a.x * SQRT_CSCALE); w[1] = (__bf16)(a.y * SQRT_CSCALE);
    w[2] = (__bf16)(a.z * SQRT_CSCALE); w[3] = (__bf16)(a.w * SQRT_CSCALE);
    w[4] = (__bf16)(b.x * SQRT_CSCALE); w[5] = (__bf16)(b.y * SQRT_CSCALE);
    w[6] = (__bf16)(b.z * SQRT_CSCALE); w[7] = (__bf16)(b.w * SQRT_CSCALE);
    *(bf16x8*)(out + i) = w;
}

// ---------------- kernel 1: fused GEMM + log2-sum-exp2 partials ----------------
// grid = 32 rowblocks x 16 colsplits = 512 blocks (2/CU), 256 threads (4 waves).
// block: rows [rbk*128,+128), cols [q*256,+256) as 16 tiles of 16 cols x K512.
__global__ __launch_bounds__(256, 2) void jl_main(const __bf16* __restrict__ rb,
                                                  float* __restrict__ pm,
                                                  float* __restrict__ ps,
                                                  float* __restrict__ pos) {
    // 4-slot ring x 16 rows x 1KB, XOR-swizzled 16B chunks within each row
    __shared__ __align__(16) char lds[4][16][1024];

    const int rbk  = blockIdx.x >> 4;   // 0..31
    const int q    = blockIdx.x & 15;   // 0..15
    const int wave = threadIdx.x >> 6;
    const int lane = threadIdx.x & 63;

    const int row0 = rbk * BM + wave * 32;   // wave's first row (32 rows)
    const int col0 = q * 256;
    const int lrow = lane & 15;
    const int lk   = lane >> 4;
    const int swz  = (lrow & 7) << 4;        // read-side XOR (byte units)
    const char* rbb = (const char*)rb;       // row stride 1024 B

    // A fragments, two 16-row halves: 32 x bf16x8 = 128 VGPR
    bf16x8 afA[16], afB[16];
    {
        const __bf16* arow = rb + (size_t)(row0 + lrow) * DDIM + lk * 8;
        #pragma unroll
        for (int kb = 0; kb < 16; ++kb) {
            afA[kb] = *(const bf16x8*)(arow + kb * 32);
            afB[kb] = *(const bf16x8*)(arow + 16 * DDIM + kb * 32);
        }
    }
    // pin: forces the compiler to drain A-load vmcnt HERE (before staging),
    // so the staging vmcnt queue holds ONLY gload_lds entries.
    #pragma unroll
    for (int kb = 0; kb < 16; ++kb) {
        asm volatile("" : "+v"(afA[kb]));
        asm volatile("" : "+v"(afB[kb]));
    }

    // coalesced swizzled staging: wave w stages rows 4w..4w+3 (1KB row/instr)
#define STAGE(T)                                                               \
    do {                                                                       \
        _Pragma("unroll")                                                      \
        for (int j_ = 0; j_ < 4; ++j_) {                                       \
            const int rr_ = wave * 4 + j_;                                     \
            const char* g_ = rbb + (size_t)(col0 + (T) * 16 + rr_) * 1024      \
                             + ((lane * 16) ^ ((rr_ & 7) << 4));               \
            GLOAD_LDS16(g_, &lds[(T) & 3][rr_][0]);                            \
        }                                                                      \
    } while (0)

    STAGE(0);
    STAGE(1);
    STAGE(2);

    float m[2], s[2][4];   // per-half running max (shared across r) kept per r
    float mm_[2][4];
    #pragma unroll
    for (int h = 0; h < 2; ++h)
        #pragma unroll
        for (int r = 0; r < 4; ++r) { mm_[h][r] = NEG_BIG; s[h][r] = 0.0f; }
    (void)m;

    for (int jt = 0; jt < NT; ++jt) {
        // counted vmcnt: tile jt's 4 loads landed; 2 newest tiles stay in flight
        if (jt < NT - 2)       asm volatile("s_waitcnt vmcnt(8)" ::: "memory");
        else if (jt == NT - 2) asm volatile("s_waitcnt vmcnt(4)" ::: "memory");
        else                   asm volatile("s_waitcnt vmcnt(0)" ::: "memory");
        __builtin_amdgcn_s_barrier();
        __builtin_amdgcn_sched_barrier(0);
        if (jt + 3 < NT) STAGE(jt + 3);

        const int cb = jt & 3;

        f32x4 accA0 = {0.f,0.f,0.f,0.f}, accA1 = {0.f,0.f,0.f,0.f};
        f32x4 accB0 = {0.f,0.f,0.f,0.f}, accB1 = {0.f,0.f,0.f,0.f};
        __builtin_amdgcn_s_setprio(1);
        #pragma unroll
        for (int kb = 0; kb < 16; ++kb) {
            bf16x8 bf = *(const bf16x8*)(&lds[cb][lrow][0] + ((kb * 64 + lk * 16) ^ swz));
            if (kb & 1) {
                accA1 = MFMA16(afA[kb], bf, accA1);
                accB1 = MFMA16(afB[kb], bf, accB1);
            } else {
                accA0 = MFMA16(afA[kb], bf, accA0);
                accB0 = MFMA16(afB[kb], bf, accB0);
            }
        }
        __builtin_amdgcn_s_setprio(0);

        f32x4 y[2];
        y[0] = accA0 + accA1;   // rows row0    + 4*lk + r, col ctile + lrow
        y[1] = accB0 + accB1;   // rows row0+16 + 4*lk + r

        const int ctile = col0 + jt * 16;   // wave-uniform

        // positive-pair tiles (uniform, rare): partner of row i is i^2048
        if (ctile == (row0 ^ 2048)) {
            #pragma unroll
            for (int r = 0; r < 4; ++r)
                if (lrow == 4 * lk + r) pos[row0 + 4 * lk + r] = y[0][r];
        }
        if (ctile == ((row0 + 16) ^ 2048)) {
            #pragma unroll
            for (int r = 0; r < 4; ++r)
                if (lrow == 4 * lk + r) pos[row0 + 16 + 4 * lk + r] = y[1][r];
        }

        const bool d0 = (ctile == row0), d1 = (ctile == row0 + 16);
        if (d0 || d1) {
            // diagonal tile (1 per wave): masked full online update
            #pragma unroll
            for (int h = 0; h < 2; ++h) {
                const bool dh = h ? d1 : d0;
                #pragma unroll
                for (int r = 0; r < 4; ++r) {
                    const bool isd = dh && (lrow == 4 * lk + r);
                    float yv = isd ? NEG_BIG : y[h][r];
                    float mn = fmaxf(mm_[h][r], yv);
                    float e  = isd ? 0.0f : __builtin_amdgcn_exp2f(yv - mn);
                    s[h][r] = s[h][r] * __builtin_amdgcn_exp2f(mm_[h][r] - mn) + e;
                    mm_[h][r] = mn;
                }
            }
        } else {
            float t0 = y[0][0] - mm_[0][0], t1 = y[0][1] - mm_[0][1];
            float t2 = y[0][2] - mm_[0][2], t3 = y[0][3] - mm_[0][3];
            float t4 = y[1][0] - mm_[1][0], t5 = y[1][1] - mm_[1][1];
            float t6 = y[1][2] - mm_[1][2], t7 = y[1][3] - mm_[1][3];
            float dmax = fmaxf(fmaxf(fmaxf(t0, t1), fmaxf(t2, t3)),
                               fmaxf(fmaxf(t4, t5), fmaxf(t6, t7)));
            if (__any(dmax > THR)) {
                #pragma unroll
                for (int h = 0; h < 2; ++h)
                    #pragma unroll
                    for (int r = 0; r < 4; ++r) {
                        float mn = fmaxf(mm_[h][r], y[h][r]);
                        s[h][r] = s[h][r] * __builtin_amdgcn_exp2f(mm_[h][r] - mn)
                                + __builtin_amdgcn_exp2f(y[h][r] - mn);
                        mm_[h][r] = mn;
                    }
            } else {
                s[0][0] += __builtin_amdgcn_exp2f(t0);
                s[0][1] += __builtin_amdgcn_exp2f(t1);
                s[0][2] += __builtin_amdgcn_exp2f(t2);
                s[0][3] += __builtin_amdgcn_exp2f(t3);
                s[1][0] += __builtin_amdgcn_exp2f(t4);
                s[1][1] += __builtin_amdgcn_exp2f(t5);
                s[1][2] += __builtin_amdgcn_exp2f(t6);
                s[1][3] += __builtin_amdgcn_exp2f(t7);
            }
        }
    }
#undef STAGE

    // merge (m,s) across the 16 lanes of each row group, write partials
    #pragma unroll
    for (int h = 0; h < 2; ++h)
        #pragma unroll
        for (int r = 0; r < 4; ++r) {
            float mm = mm_[h][r], ss = s[h][r];
            #pragma unroll
            for (int off = 1; off < 16; off <<= 1) {
                float mo = __shfl_xor(mm, off, 64);
                float so = __shfl_xor(ss, off, 64);
                float mn = fmaxf(mm, mo);
                ss = ss * __builtin_amdgcn_exp2f(mm - mn)
                   + so * __builtin_amdgcn_exp2f(mo - mn);
                mm = mn;
            }
            if (lrow == 0) {
                const int grow = row0 + 16 * h + 4 * lk + r;
                pm[grow * NSPLIT + q] = mm;
                ps[grow * NSPLIT + q] = ss;
            }
        }
}

// ---------------- kernel 2a: per-row loss + per-block partial sum ----------------
__global__ void jl_rowloss(const float* __restrict__ pm, const float* __restrict__ ps,
                           const float* __restrict__ pos, float* __restrict__ part) {
    __shared__ float red[256];
    const int t = threadIdx.x;
    const int row = blockIdx.x * 256 + t;
    float mb = NEG_BIG;
    #pragma unroll
    for (int qq = 0; qq < NSPLIT; ++qq) mb = fmaxf(mb, pm[row * NSPLIT + qq]);
    float st = 0.0f;
    #pragma unroll
    for (int qq = 0; qq < NSPLIT; ++qq)
        st += ps[row * NSPLIT + qq] * __builtin_amdgcn_exp2f(pm[row * NSPLIT + qq] - mb);
    red[t] = mb + __builtin_amdgcn_logf(st) - pos[row];
    __syncthreads();
    for (int off = 128; off > 0; off >>= 1) {
        if (t < off) red[t] += red[t + off];
        __syncthreads();
    }
    if (t == 0) part[blockIdx.x] = red[0];
}

// ---------------- kernel 2b: final reduce ----------------
__global__ void jl_final(const float* __restrict__ part, float* __restrict__ out) {
    const int t = threadIdx.x;
    float v = (t < NROWS / 256) ? part[t] : 0.0f;
    #pragma unroll
    for (int off = 1; off < 16; off <<= 1) v += __shfl_xor(v, off, 64);
    if (t == 0) out[0] = v * (LN2 / (float)NROWS);
}

extern "C" void kernel_launch(void* const* d_in, const int* in_sizes, int n_in,
                              void* d_out, int out_size, void* d_ws, size_t ws_size,
                              hipStream_t stream) {
    const float* rep = (const float*)d_in[0];
    float* out = (float*)d_out;

    __bf16* rbuf = (__bf16*)d_ws;
    float*  pm   = (float*)(rbuf + (size_t)NROWS * DDIM);
    float*  ps   = pm + NROWS * NSPLIT;
    float*  pos  = ps + NROWS * NSPLIT;
    float*  part = pos + NROWS;

    jl_cvt<<<(NROWS * DDIM) / (256 * 8), 256, 0, stream>>>(rep, rbuf);
    jl_main<<<32 * NSPLIT, 256, 0, stream>>>(rbuf, pm, ps, pos);
    jl_rowloss<<<NROWS / 256, 256, 0, stream>>>(pm, ps, pos, part);
    jl_final<<<1, 64, 0, stream>>>(part, out);
}